// Round 17
// baseline (3156.096 us; speedup 1.0000x reference)
//
#include <hip/hip_runtime.h>
#include <math.h>

// Conv1D(k=2,F=64,relu) -> LSTM1(H=100, relu cell, seq) -> LSTM2 (last) ->
// Dense(3) -> softmax.  B=128, T=2048, T'=2047.
//
// Round-22 = r20 (1844.6us best) extended to BATCH-2 per block.
//  Evidence r14-r21: step time (~900ns) is invariant to fdot2 count (+-10%),
//  DS-inst count (-45%), vmcnt drains, barrier width -> a FIXED per-step
//  cost (rendezvous + LDS turnaround + dep-chain latency) dominates.
//  Amortize it: each producer block runs LSTM1 for TWO batches (shared
//  weight registers -- zero extra weight regs; accumulators/operand reads/
//  ring width x2), each consumer block LSTM2 for two.  64+64 blocks.
//  r19's batch-16 failure mode (16x transport through frag layouts) does
//  not apply at x2 with the proven scalar structure.
//  __launch_bounds__(512,1): 1 block/CU, 2 waves/SIMD, 256-reg budget.
//  Everything else r20-identical: (p,g2,kh) mapping, DPP psum2/xswap2,
//  packed f16 weights, per-batch 4-slot rings, lgkmcnt-only step_barrier,
//  chunk-end vmcnt(0) + release flag (per block-pair).

typedef _Float16 h2 __attribute__((ext_vector_type(2)));

#define TT 2048
#define TP 2047
#define HH 100
#define G4 400
#define FF 64
#define PB 64                // block pairs; batches 2*pr, 2*pr+1

#define X1R 176              // producer operand row halves (2x88)
#define CBQ 104              // consumer row halves (100 + pad4)
#define NPW (400 * 88)       // producer packed h2
#define NCW (400 * 100)      // consumer packed h2
#define CHK 64
#define NCHUNK 32
#define RINGC 4
#define CHUNK_DW (CHK * 50)  // 3200 dwords per ring slot (per batch)

// ws layout in 4B units
#define WS_FLAGS (NPW + NCW)       // pflag[64] @ +0, aflag[64] @ +128
#define WS_RING  (WS_FLAGS + 256)  // 128 batches * RINGC * CHUNK_DW dwords

#define FD2(w, xs, acc) acc = __builtin_amdgcn_fdot2(w, xs, acc, false)
#define B2(f) __builtin_bit_cast(h2, f)

// DPP quad_perm: 0xB1 = xor-1, 0x4E = xor-2 (proven r6-r21)
static __device__ __forceinline__ float psum2(float z) {
    int p = __builtin_amdgcn_update_dpp(0, __builtin_bit_cast(int, z),
                                        0xB1, 0xF, 0xF, true);
    return z + __builtin_bit_cast(float, p);
}
static __device__ __forceinline__ float xswap2(float z) {
    int p = __builtin_amdgcn_update_dpp(0, __builtin_bit_cast(int, z),
                                        0x4E, 0xF, 0xF, true);
    return __builtin_bit_cast(float, p);
}
static __device__ __forceinline__ float sig(float z) {
    return 1.0f / (1.0f + __expf(-z));
}
// per-step barrier: order LDS (lgkmcnt) but DO NOT drain vmcnt
static __device__ __forceinline__ void step_barrier() {
    __builtin_amdgcn_sched_barrier(0);
    asm volatile("s_waitcnt lgkmcnt(0)" ::: "memory");
    __builtin_amdgcn_sched_barrier(0);
    __builtin_amdgcn_s_barrier();
    __builtin_amdgcn_sched_barrier(0);
}

// ---------------- prep kernel (r20-identical) -------------------------------
__global__ void prep_weights(const float* __restrict__ w1, const float* __restrict__ u1,
                             const float* __restrict__ w2, const float* __restrict__ u2,
                             h2* __restrict__ ws)
{
    const int idx = blockIdx.x * 256 + threadIdx.x;
    if (idx >= NPW + NCW) return;
    float lo = 0.f, hi = 0.f;
    if (idx < NPW) {
        const int rt = idx / 88, r = idx % 88;
        const int qq = (r >> 2) * 2 + ((r & 3) >> 1);
        const int gs = r & 1;
        const int p = rt >> 2, g2 = (rt >> 1) & 1, kh = rt & 1;
        const int col = (2 * g2 + gs) * HH + p;
        const int E0 = 2 * qq;
#pragma unroll
        for (int e = 0; e < 2; ++e) {
            const int E = E0 + e;
            float v = 0.f;
            if (E < 82) {
                const int k = kh * 82 + E;
                v = (k < FF) ? w1[k * G4 + col] : u1[(k - FF) * G4 + col];
            }
            if (e == 0) lo = v; else hi = v;
        }
    } else {
        const int i2 = idx - NPW;
        const int rt = i2 / 100, r = i2 % 100;
        const int qq = (r >> 2) * 2 + ((r & 3) >> 1);
        const int gs = r & 1;
        const int p = rt >> 2, g2 = (rt >> 1) & 1, kh = rt & 1;
        const int col = (2 * g2 + gs) * HH + p;
        const int k0 = 2 * qq;
        const float* M = kh ? u2 : w2;
        lo = M[k0 * G4 + col];
        hi = M[(k0 + 1) * G4 + col];
    }
    ws[idx] = h2{(_Float16)lo, (_Float16)hi};
}

// unrolled 100-long dot over a row base (12 float4 + float2 tail)
#define CDOT(base, za0, za1, zb0, zb1) { \
    const float4* vb = (const float4*)(base); \
_Pragma("unroll") \
    for (int r2 = 0; r2 < 12; ++r2) { \
        const float4 v = vb[r2]; \
        FD2(wa[4*r2+0], B2(v.x), za0); FD2(wb[4*r2+0], B2(v.x), zb0); \
        FD2(wa[4*r2+1], B2(v.y), za1); FD2(wb[4*r2+1], B2(v.y), zb1); \
        FD2(wa[4*r2+2], B2(v.z), za0); FD2(wb[4*r2+2], B2(v.z), zb0); \
        FD2(wa[4*r2+3], B2(v.w), za1); FD2(wb[4*r2+3], B2(v.w), zb1); \
    } \
    { const float2 tv = *(const float2*)((base) + 96); \
      FD2(wa[48], B2(tv.x), za0); FD2(wb[48], B2(tv.x), zb0); \
      FD2(wa[49], B2(tv.y), za1); FD2(wb[49], B2(tv.y), zb1); } }

// unrolled 88-long producer dot
#define PDOT(base, za0, za1, zb0, zb1) { \
    const float4* vb = (const float4*)(base); \
_Pragma("unroll") \
    for (int r2 = 0; r2 < 11; ++r2) { \
        const float4 v = vb[r2]; \
        FD2(wa[4*r2+0], B2(v.x), za0); FD2(wb[4*r2+0], B2(v.x), zb0); \
        FD2(wa[4*r2+1], B2(v.y), za1); FD2(wb[4*r2+1], B2(v.y), zb1); \
        FD2(wa[4*r2+2], B2(v.z), za0); FD2(wb[4*r2+2], B2(v.z), zb0); \
        FD2(wa[4*r2+3], B2(v.w), za1); FD2(wb[4*r2+3], B2(v.w), zb1); \
    } }

// gate combine + cell update + h
#define GCELL(zaS, zbS, bLv, bHv, cc, hh_) { \
    const float oa = xswap2(zaS), ob = xswap2(zbS); \
    const float zi = g2 ? oa  : zaS; \
    const float zf = g2 ? ob  : zbS; \
    const float zg = g2 ? zaS : oa; \
    const float zo = g2 ? zbS : ob; \
    cc = fmaf(sig(zf), cc, sig(zi) * fmaxf(zg, 0.f)); \
    hh_ = sig(zo) * fmaxf(cc, 0.f); }

// ---------------- main kernel ----------------------------------------------
__global__ __launch_bounds__(512, 1)
void fused_lstm_kernel(const float* __restrict__ s,       // [B,T]
                       const float* __restrict__ conv_w,  // [2,1,F]
                       const float* __restrict__ conv_b,  // [F]
                       const float* __restrict__ b1,
                       const float* __restrict__ b2,
                       const float* __restrict__ dw, const float* __restrict__ db,
                       h2* __restrict__ wpk,              // weights + flags + rings
                       float* __restrict__ out)           // [B,3]
{
    const int tid  = threadIdx.x;
    const int bb   = blockIdx.x;
    const bool prod = bb < PB;
    const int pr   = prod ? bb : bb - PB;
    const int b0   = 2 * pr, b1i = 2 * pr + 1;

    int* pflag = (int*)(wpk + WS_FLAGS) + pr;
    int* aflag = (int*)(wpk + WS_FLAGS) + 128 + pr;
    unsigned* ring0 = (unsigned*)(wpk + WS_RING) + (size_t)b0  * (RINGC * CHUNK_DW);
    unsigned* ring1 = (unsigned*)(wpk + WS_RING) + (size_t)b1i * (RINGC * CHUNK_DW);

    __shared__ float s_buf[2 * TT];                    // producer: 2 input rows
    __shared__ __align__(16) _Float16 X1[4 * X1R];     // [bat][slot][176]
    __shared__ __align__(16) _Float16 CB[2 * CHK * CBQ];  // [bat][64][104]
    __shared__ __align__(16) _Float16 HR[4 * CBQ];     // [bat][slot][104]

    if (prod) {
        for (int i = tid; i < 2 * TT; i += 512) {
            const int bat = i >> 11, off = i & (TT - 1);
            s_buf[i] = s[(size_t)(2 * pr + bat) * TT + off];
        }
        if (tid < 2 * X1R) ((unsigned*)X1)[tid] = 0u;  // 4*176 halves = 352 dwords
    } else {
        if (tid < 2 * CBQ) ((unsigned*)HR)[tid] = 0u;  // 4*104 halves = 208 dwords
        if (tid < CHK * 4) {                           // CB pad dwords both batches
            const int bat = tid & 1, r = tid >> 2, e = (tid >> 1) & 1;
            ((unsigned*)(CB + bat * CHK * CBQ))[r * 52 + 50 + e] = 0u;
        }
    }
    __syncthreads();                                   // (A)

    if (prod) {
        // ====== PRODUCER block: conv (wave 7) + LSTM1 x2 batches ======
        if (tid < 448) {
            const int rt = tid;
            const int active = rt < 400;
            const int lrt = active ? rt : 0;
            const int p  = lrt >> 2;
            const int g2 = (lrt >> 1) & 1;
            const int kh = lrt & 1;
            const int cL = (2 * g2) * HH + p;

            h2 wa[44], wb[44];
            {
                const float4* w4 = (const float4*)(wpk + (size_t)lrt * 88);
#pragma unroll
                for (int j = 0; j < 22; ++j) {
                    const float4 v = w4[j];
                    wa[2*j]   = B2(v.x); wb[2*j]   = B2(v.y);
                    wa[2*j+1] = B2(v.z); wb[2*j+1] = B2(v.w);
                }
            }
            const float bL = b1[cL], bH = b1[cL + HH];
            const int hoff = (p < 18) ? (64 + p) : (p + 70);
            __syncthreads();                           // (B)

            float cA = 0.0f, cB2 = 0.0f;
            for (int t = 0; t < TP; ++t) {
                if ((t & 63) == 0) {                   // chunk start: ring credit
                    const int k = t >> 6;
                    if (tid == 0 && k >= RINGC) {
                        int g = 0;
                        while (__hip_atomic_load(aflag, __ATOMIC_ACQUIRE,
                                                 __HIP_MEMORY_SCOPE_AGENT) < k - (RINGC - 1)
                               && g < 50000000) { ++g; __builtin_amdgcn_s_sleep(8); }
                    }
                    __syncthreads();
                }
                if (active) {
                    const int cs = (t & 1) * X1R, ns = ((t & 1) ^ 1) * X1R;
                    float zaA0 = 0.f, zaA1 = 0.f, zbA0 = 0.f, zbA1 = 0.f;
                    float zaB0 = 0.f, zaB1 = 0.f, zbB0 = 0.f, zbB1 = 0.f;
                    PDOT(X1 + cs + kh * 88, zaA0, zaA1, zbA0, zbA1)
                    PDOT(X1 + 2 * X1R + cs + kh * 88, zaB0, zaB1, zbB0, zbB1)
                    const float zaSA = psum2(zaA0 + zaA1) + bL;
                    const float zbSA = psum2(zbA0 + zbA1) + bH;
                    const float zaSB = psum2(zaB0 + zaB1) + bL;
                    const float zbSB = psum2(zbB0 + zbB1) + bH;
                    float hA, hB;
                    GCELL(zaSA, zbSA, bL, bH, cA, hA)
                    GCELL(zaSB, zbSB, bL, bH, cB2, hB)
                    if ((rt & 3) == 0) {
                        const _Float16 hqA = (_Float16)hA;
                        const _Float16 hqB = (_Float16)hB;
                        X1[ns + hoff] = hqA;
                        X1[2 * X1R + ns + hoff] = hqB;
                        const unsigned hbA = (unsigned)__builtin_bit_cast(unsigned short, hqA);
                        const unsigned hbB = (unsigned)__builtin_bit_cast(unsigned short, hqB);
                        const unsigned prtA =
                            (unsigned)__builtin_amdgcn_ds_swizzle((int)hbA, 0x101F) & 0xFFFFu;
                        const unsigned prtB =
                            (unsigned)__builtin_amdgcn_ds_swizzle((int)hbB, 0x101F) & 0xFFFFu;
                        if (!(p & 1)) {
                            const size_t roff = (size_t)((t >> 6) & 3) * CHUNK_DW
                                              + (t & 63) * 50 + (p >> 1);
                            __hip_atomic_store(ring0 + roff, hbA | (prtA << 16),
                                               __ATOMIC_RELAXED, __HIP_MEMORY_SCOPE_AGENT);
                            __hip_atomic_store(ring1 + roff, hbB | (prtB << 16),
                                               __ATOMIC_RELAXED, __HIP_MEMORY_SCOPE_AGENT);
                        }
                    }
                    if (((t & 63) == 63) || (t == TP - 1))
                        asm volatile("s_waitcnt vmcnt(0)" ::: "memory");
                }
                step_barrier();                        // (C)
                if (tid == 0 && (((t & 63) == 63) || (t == TP - 1)))
                    __hip_atomic_fetch_add(pflag, 1, __ATOMIC_RELEASE,
                                           __HIP_MEMORY_SCOPE_AGENT);
            }
        } else {
            // conv wave: threads 448-511, one filter each, both batches
            const int f = tid - 448;
            const float cv0 = conv_w[f], cv1 = conv_w[FF + f], cb0 = conv_b[f];
            X1[f] = (_Float16)fmaxf(fmaf(s_buf[0], cv0, fmaf(s_buf[1], cv1, cb0)), 0.f);
            X1[2 * X1R + f] = (_Float16)fmaxf(
                fmaf(s_buf[TT], cv0, fmaf(s_buf[TT + 1], cv1, cb0)), 0.f);
            __syncthreads();                           // (B)
            for (int t = 0; t < TP; ++t) {
                if ((t & 63) == 0) __syncthreads();    // chunk-start companion
                if (t + 1 < TP) {
                    const int ns = ((t & 1) ^ 1) * X1R;
                    X1[ns + f] = (_Float16)fmaxf(
                        fmaf(s_buf[t + 1], cv0, fmaf(s_buf[t + 2], cv1, cb0)), 0.f);
                    X1[2 * X1R + ns + f] = (_Float16)fmaxf(
                        fmaf(s_buf[TT + t + 1], cv0, fmaf(s_buf[TT + t + 2], cv1, cb0)), 0.f);
                }
                step_barrier();                        // (C)
            }
        }
    } else {
        // ====== CONSUMER block: LSTM2 x2 + dense + softmax ======
        if (tid < 448) {
            const int rt = tid;
            const int active = rt < 400;
            const int lrt = active ? rt : 0;
            const int p  = lrt >> 2;
            const int g2 = (lrt >> 1) & 1;
            const int kh = lrt & 1;
            const int cL = (2 * g2) * HH + p;

            h2 wa[50], wb[50];
            {
                const float4* w4 = (const float4*)(wpk + NPW + (size_t)lrt * 100);
#pragma unroll
                for (int j = 0; j < 25; ++j) {
                    const float4 v = w4[j];
                    wa[2*j]   = B2(v.x); wb[2*j]   = B2(v.y);
                    wa[2*j+1] = B2(v.z); wb[2*j+1] = B2(v.w);
                }
            }
            const float bL = b2[cL], bH = b2[cL + HH];
            __syncthreads();                           // (B)

            float cA = 0.0f, cB2 = 0.0f;
            for (int k = 0; k < NCHUNK; ++k) {
                if (tid == 0) {
                    int g = 0;
                    while (__hip_atomic_load(pflag, __ATOMIC_ACQUIRE,
                                             __HIP_MEMORY_SCOPE_AGENT) < k + 1
                           && g < 50000000) { ++g; __builtin_amdgcn_s_sleep(8); }
                }
                __syncthreads();                       // chunk ready
                const int csz = (TP - (k << 6) < CHK) ? (TP - (k << 6)) : CHK;
                unsigned* gsA = ring0 + (k & 3) * CHUNK_DW;
                unsigned* gsB = ring1 + (k & 3) * CHUNK_DW;
                unsigned* cbA = (unsigned*)CB;
                unsigned* cbB = (unsigned*)(CB + CHK * CBQ);
                for (int d = tid; d < csz * 50; d += 448) {
                    const int dst = (d / 50) * 52 + (d % 50);
                    cbA[dst] = __hip_atomic_load(gsA + d, __ATOMIC_RELAXED,
                                                 __HIP_MEMORY_SCOPE_AGENT);
                    cbB[dst] = __hip_atomic_load(gsB + d, __ATOMIC_RELAXED,
                                                 __HIP_MEMORY_SCOPE_AGENT);
                }
                __syncthreads();                       // staged
                if (tid == 0)
                    __hip_atomic_fetch_add(aflag, 1, __ATOMIC_RELAXED,
                                           __HIP_MEMORY_SCOPE_AGENT);
                for (int lt = 0; lt < csz; ++lt) {
                    const int t = (k << 6) + lt;
                    if (active) {
                        const _Float16* baseA = kh ? (HR + (t & 1) * CBQ)
                                                   : (CB + lt * CBQ);
                        const _Float16* baseB = kh ? (HR + 2 * CBQ + (t & 1) * CBQ)
                                                   : (CB + CHK * CBQ + lt * CBQ);
                        float zaA0 = 0.f, zaA1 = 0.f, zbA0 = 0.f, zbA1 = 0.f;
                        float zaB0 = 0.f, zaB1 = 0.f, zbB0 = 0.f, zbB1 = 0.f;
                        CDOT(baseA, zaA0, zaA1, zbA0, zbA1)
                        CDOT(baseB, zaB0, zaB1, zbB0, zbB1)
                        const float zaSA = psum2(zaA0 + zaA1) + bL;
                        const float zbSA = psum2(zbA0 + zbA1) + bH;
                        const float zaSB = psum2(zaB0 + zaB1) + bL;
                        const float zbSB = psum2(zbB0 + zbB1) + bH;
                        float hA, hB;
                        GCELL(zaSA, zbSA, bL, bH, cA, hA)
                        GCELL(zaSB, zbSB, bL, bH, cB2, hB)
                        if ((rt & 3) == 0) {
                            HR[((t & 1) ^ 1) * CBQ + p] = (_Float16)hA;
                            HR[2 * CBQ + ((t & 1) ^ 1) * CBQ + p] = (_Float16)hB;
                        }
                    }
                    step_barrier();                    // (C)
                }
            }

            // final h2(t=2046) in slot 1 of each batch's HR
            if (rt < 2) {
                const _Float16* hf = HR + rt * 2 * CBQ + CBQ;
                float l[3];
#pragma unroll
                for (int a = 0; a < 3; ++a) {
                    float acc = db[a];
                    for (int j = 0; j < HH; ++j)
                        acc = fmaf((float)hf[j], dw[j * 3 + a], acc);
                    l[a] = acc;
                }
                const float m = fmaxf(l[0], fmaxf(l[1], l[2]));
                const float e0 = __expf(l[0] - m), e1 = __expf(l[1] - m), e2 = __expf(l[2] - m);
                const float inv = 1.0f / (e0 + e1 + e2);
                const int bo = 2 * pr + rt;
                out[bo * 3 + 0] = e0 * inv;
                out[bo * 3 + 1] = e1 * inv;
                out[bo * 3 + 2] = e2 * inv;
            }
        } else {
            // threads 448-511: barrier companions
            __syncthreads();                           // (B)
            for (int k = 0; k < NCHUNK; ++k) {
                __syncthreads();                       // chunk ready
                const int csz = (TP - (k << 6) < CHK) ? (TP - (k << 6)) : CHK;
                __syncthreads();                       // staged
                for (int lt = 0; lt < csz; ++lt)
                    step_barrier();                    // (C)
            }
        }
    }
}

// ---------------- launch ----------------------------------------------------
extern "C" void kernel_launch(void* const* d_in, const int* in_sizes, int n_in,
                              void* d_out, int out_size, void* d_ws, size_t ws_size,
                              hipStream_t stream) {
    const float* s      = (const float*)d_in[0];
    const float* conv_w = (const float*)d_in[1];
    const float* conv_b = (const float*)d_in[2];
    const float* w1     = (const float*)d_in[3];
    const float* u1     = (const float*)d_in[4];
    const float* b1     = (const float*)d_in[5];
    const float* w2     = (const float*)d_in[6];
    const float* u2     = (const float*)d_in[7];
    const float* b2     = (const float*)d_in[8];
    const float* dw     = (const float*)d_in[9];
    const float* db     = (const float*)d_in[10];

    h2* ws = (h2*)d_ws;
    hipMemsetAsync((void*)((int*)(ws + WS_FLAGS)), 0, 256 * sizeof(int), stream);
    const int nh2 = NPW + NCW;
    prep_weights<<<(nh2 + 255) / 256, 256, 0, stream>>>(w1, u1, w2, u2, ws);
    fused_lstm_kernel<<<2 * PB, 512, 0, stream>>>(
        s, conv_w, conv_b, b1, b2, dw, db, ws, (float*)d_out);
}

// Round 18
// 2155.997 us; speedup vs baseline: 1.4639x; 1.4639x over previous
//
#include <hip/hip_runtime.h>
#include <math.h>

// Conv1D(k=2,F=64,relu) -> LSTM1(H=100, relu cell, seq) -> LSTM2 (last) ->
// Dense(3) -> softmax.  B=128, T=2048, T'=2047.
//
// Round-23: 4-WAVE blocks (256 thr) -- clean barrier-width test.
//  Evidence r19/r20/r22: step = fixed(~700ns) + var(~100-200ns/batch); fixed
//  is invariant to instruction mix -> it is the multi-wave rendezvous
//  (s_barrier + resume + LDS turnaround).  Halve the rendezvous width:
//  256-thread blocks, (unit p = rt>>1, gate-pair g2 = rt&1) mapping with
//  FULL-K per thread: producer K=[x64|h100]=164 (82 h2 x 2 gates, 41 f4
//  weight loads, 20 f4 + 1 f2 operand reads); consumer K=[h1 100|h2 100]
//  (100 h2 x 2 gates).  No psum2 (no K split); gate exchange = one xor-1
//  DPP (partner rt^1, same p).  Pair-redundant cell; g2==0 writes h.
//  conv on producer lanes 200-255 (f=rt-200, +56+f for f<8).
//  launch_bounds(256,1): 1 block/CU, 1 wave/SIMD, no spill at 164-200
//  weight h2 + misc.  Ring/flag/chunk protocol r20-verbatim; lgkmcnt-only
//  step_barrier; chunk-end vmcnt(0)+release.
//  Go/no-go: >=1845us -> fixed cost is width-invariant -> declare the
//  2047 x ~900ns sequential-sync floor.

typedef _Float16 h2 __attribute__((ext_vector_type(2)));

#define TT 2048
#define TP 2047
#define HH 100
#define G4 400
#define FF 64
#define NB 128

#define X1R 168              // producer operand row halves (164 + pad4)
#define CBQ 104              // consumer h1 row halves (100 + pad4)
#define NPW (200 * 164)      // producer packed h2 (82 x 2 gates / thread)
#define NCW (200 * 200)      // consumer packed h2 (100 x 2 gates / thread)
#define CHK 64
#define NCHUNK 32
#define RINGC 4
#define CHUNK_DW (CHK * 50)  // 3200 dwords per ring slot

// ws layout in 4B units
#define WS_FLAGS (NPW + NCW)       // pflag[128], aflag[128]
#define WS_RING  (WS_FLAGS + 256)  // 128 * RINGC * CHUNK_DW dwords

#define FD2(w, xs, acc) acc = __builtin_amdgcn_fdot2(w, xs, acc, false)
#define B2(f) __builtin_bit_cast(h2, f)

// DPP quad_perm xor-1 value exchange (partner rt^1, same unit p)
static __device__ __forceinline__ float xswap1(float z) {
    int p = __builtin_amdgcn_update_dpp(0, __builtin_bit_cast(int, z),
                                        0xB1, 0xF, 0xF, true);
    return __builtin_bit_cast(float, p);
}
static __device__ __forceinline__ float sig(float z) {
    return 1.0f / (1.0f + __expf(-z));
}
// per-step barrier: order LDS only; ring stores stay in flight
static __device__ __forceinline__ void step_barrier() {
    __builtin_amdgcn_sched_barrier(0);
    asm volatile("s_waitcnt lgkmcnt(0)" ::: "memory");
    __builtin_amdgcn_sched_barrier(0);
    __builtin_amdgcn_s_barrier();
    __builtin_amdgcn_sched_barrier(0);
}

// ---------------- prep kernel: pack weights f16 per (thread, full-K) -------
// thread rt = 2*p + g2 ; gates cL = (2*g2)*100+p, cH = cL+100.
// float4 j = (a_{2j}, b_{2j}, a_{2j+1}, b_{2j+1}),  a=cL col, b=cH col.
__global__ void prep_weights(const float* __restrict__ w1, const float* __restrict__ u1,
                             const float* __restrict__ w2, const float* __restrict__ u2,
                             h2* __restrict__ ws)
{
    const int idx = blockIdx.x * 256 + threadIdx.x;
    if (idx >= NPW + NCW) return;
    float lo = 0.f, hi = 0.f;
    if (idx < NPW) {
        // producer: 164 h2/thread = 41 float4; K = [x(64) | h1(100)]
        const int rt = idx / 164, r = idx % 164;
        const int qq = (r >> 2) * 2 + ((r & 3) >> 1);   // h2 pair 0..81
        const int gs = r & 1;                           // 0 -> cL, 1 -> cH
        const int p = rt >> 1, g2 = rt & 1;
        const int col = (2 * g2 + gs) * HH + p;
        const int k0 = 2 * qq;                          // 0..162
#pragma unroll
        for (int e = 0; e < 2; ++e) {
            const int k = k0 + e;
            const float v = (k < FF) ? w1[k * G4 + col] : u1[(k - FF) * G4 + col];
            if (e == 0) lo = v; else hi = v;
        }
    } else {
        // consumer: 200 h2/thread = 50 float4; K = [h1(100) | h2(100)]
        const int i2 = idx - NPW;
        const int rt = i2 / 200, r = i2 % 200;
        const int qq = (r >> 2) * 2 + ((r & 3) >> 1);   // 0..99
        const int gs = r & 1;
        const int p = rt >> 1, g2 = rt & 1;
        const int col = (2 * g2 + gs) * HH + p;
        const int k0 = 2 * qq;                          // 0..198
#pragma unroll
        for (int e = 0; e < 2; ++e) {
            const int k = k0 + e;
            const float v = (k < HH) ? w2[k * G4 + col] : u2[(k - HH) * G4 + col];
            if (e == 0) lo = v; else hi = v;
        }
    }
    ws[idx] = h2{(_Float16)lo, (_Float16)hi};
}

// producer full-K dot: 20 float4 + 1 float2 (halves 0..163)
#define PDOTF(base) { const float4* vb = (const float4*)(base); \
_Pragma("unroll") \
    for (int r2 = 0; r2 < 20; ++r2) { \
        const float4 v = vb[r2]; \
        FD2(wa[4*r2+0], B2(v.x), za0); FD2(wb[4*r2+0], B2(v.x), zb0); \
        FD2(wa[4*r2+1], B2(v.y), za1); FD2(wb[4*r2+1], B2(v.y), zb1); \
        FD2(wa[4*r2+2], B2(v.z), za0); FD2(wb[4*r2+2], B2(v.z), zb0); \
        FD2(wa[4*r2+3], B2(v.w), za1); FD2(wb[4*r2+3], B2(v.w), zb1); \
    } \
    { const float2 tv = *(const float2*)((base) + 160); \
      FD2(wa[80], B2(tv.x), za0); FD2(wb[80], B2(tv.x), zb0); \
      FD2(wa[81], B2(tv.y), za1); FD2(wb[81], B2(tv.y), zb1); } }

// consumer half-dot: 12 float4 + 1 float2 over 100 halves, weight offset WO
#define CDOTH(base, WO) { const float4* vb = (const float4*)(base); \
_Pragma("unroll") \
    for (int r2 = 0; r2 < 12; ++r2) { \
        const float4 v = vb[r2]; \
        FD2(wa[(WO)+4*r2+0], B2(v.x), za0); FD2(wb[(WO)+4*r2+0], B2(v.x), zb0); \
        FD2(wa[(WO)+4*r2+1], B2(v.y), za1); FD2(wb[(WO)+4*r2+1], B2(v.y), zb1); \
        FD2(wa[(WO)+4*r2+2], B2(v.z), za0); FD2(wb[(WO)+4*r2+2], B2(v.z), zb0); \
        FD2(wa[(WO)+4*r2+3], B2(v.w), za1); FD2(wb[(WO)+4*r2+3], B2(v.w), zb1); \
    } \
    { const float2 tv = *(const float2*)((base) + 96); \
      FD2(wa[(WO)+48], B2(tv.x), za0); FD2(wb[(WO)+48], B2(tv.x), zb0); \
      FD2(wa[(WO)+49], B2(tv.y), za1); FD2(wb[(WO)+49], B2(tv.y), zb1); } }

// gate combine (partner rt^1) + cell update
#define GCELL1(zaS, zbS, cc, hh_) { \
    const float oa = xswap1(zaS), ob = xswap1(zbS); \
    const float zi = g2 ? oa  : zaS; \
    const float zf = g2 ? ob  : zbS; \
    const float zg = g2 ? zaS : oa; \
    const float zo = g2 ? zbS : ob; \
    cc = fmaf(sig(zf), cc, sig(zi) * fmaxf(zg, 0.f)); \
    hh_ = sig(zo) * fmaxf(cc, 0.f); }

// ---------------- main kernel ----------------------------------------------
__global__ __launch_bounds__(256, 1)
void fused_lstm_kernel(const float* __restrict__ s,       // [B,T]
                       const float* __restrict__ conv_w,  // [2,1,F]
                       const float* __restrict__ conv_b,  // [F]
                       const float* __restrict__ b1,
                       const float* __restrict__ b2,
                       const float* __restrict__ dw, const float* __restrict__ db,
                       h2* __restrict__ wpk,              // weights + flags + ring
                       float* __restrict__ out)           // [B,3]
{
    const int tid  = threadIdx.x;
    const int bb   = blockIdx.x;
    const int b    = bb & (NB - 1);
    const bool prod = bb < NB;

    int* pflag = (int*)(wpk + WS_FLAGS) + b;
    int* aflag = (int*)(wpk + WS_FLAGS) + 128 + b;
    unsigned* ring = (unsigned*)(wpk + WS_RING) + (size_t)b * (RINGC * CHUNK_DW);

    __shared__ float s_buf[TT];                        // producer only
    __shared__ __align__(16) _Float16 X1[2 * X1R];     // producer operand ring
    __shared__ __align__(16) _Float16 CB[CHK * CBQ];   // consumer staged chunk
    __shared__ __align__(16) _Float16 HR[2 * CBQ];     // consumer h2 ring

    if (prod) {
        for (int i = tid; i < TT; i += 256) s_buf[i] = s[(size_t)b * TT + i];
        if (tid < X1R) ((unsigned*)X1)[tid] = 0u;      // both slots zero
    } else {
        if (tid < CBQ) ((unsigned*)HR)[tid] = 0u;
        if (tid < CHK * 2)                             // CB pad dwords [50,52)/row
            ((unsigned*)CB)[(tid >> 1) * 52 + 50 + (tid & 1)] = 0u;
    }
    __syncthreads();                                   // (A)

    if (prod) {
        // ====== PRODUCER block: LSTM1 (rt<200) + conv (rt 200-255) ======
        const int rt = tid;
        const int active = rt < 200;
        const int lrt = active ? rt : 0;
        const int p  = lrt >> 1;
        const int g2 = lrt & 1;
        const int cL = (2 * g2) * HH + p;

        h2 wa[82], wb[82];
        {
            const float4* w4 = (const float4*)(wpk + (size_t)lrt * 164);
#pragma unroll
            for (int j = 0; j < 41; ++j) {
                const float4 v = w4[j];
                wa[2*j]   = B2(v.x); wb[2*j]   = B2(v.y);
                wa[2*j+1] = B2(v.z); wb[2*j+1] = B2(v.w);
            }
        }
        const float bL = b1[cL], bH = b1[cL + HH];

        const int f1 = rt - 200;                       // conv lanes 200-255
        float cv0 = 0.f, cv1 = 0.f, cb0 = 0.f, cv0b = 0.f, cv1b = 0.f, cb0b = 0.f;
        if (!active) {
            cv0 = conv_w[f1]; cv1 = conv_w[FF + f1]; cb0 = conv_b[f1];
            if (f1 < 8) { cv0b = conv_w[56 + f1]; cv1b = conv_w[FF + 56 + f1]; cb0b = conv_b[56 + f1]; }
        }
        if (!active) {                                 // x(0) into slot 0
            X1[f1] = (_Float16)fmaxf(fmaf(s_buf[0], cv0, fmaf(s_buf[1], cv1, cb0)), 0.f);
            if (f1 < 8)
                X1[56 + f1] = (_Float16)fmaxf(fmaf(s_buf[0], cv0b, fmaf(s_buf[1], cv1b, cb0b)), 0.f);
        }
        __syncthreads();                               // (B)

        float c = 0.0f;
        for (int t = 0; t < TP; ++t) {
            if ((t & 63) == 0) {                       // chunk start: ring credit
                const int k = t >> 6;
                if (tid == 0 && k >= RINGC) {
                    int g = 0;
                    while (__hip_atomic_load(aflag, __ATOMIC_ACQUIRE,
                                             __HIP_MEMORY_SCOPE_AGENT) < k - (RINGC - 1)
                           && g < 50000000) { ++g; __builtin_amdgcn_s_sleep(8); }
                }
                __syncthreads();
            }
            if (active) {
                _Float16* cur = X1 + (t & 1) * X1R;
                _Float16* nx1 = X1 + ((t & 1) ^ 1) * X1R;
                float za0 = 0.f, za1 = 0.f, zb0 = 0.f, zb1 = 0.f;
                PDOTF(cur)
                const float zaS = za0 + za1 + bL;
                const float zbS = zb0 + zb1 + bH;
                float h;
                GCELL1(zaS, zbS, c, h)
                if (!g2) {                             // even rt = 2p writes h[p]
                    const _Float16 hq = (_Float16)h;
                    nx1[FF + p] = hq;                  // h1 for LSTM1(t+1)
                    const unsigned hb = (unsigned)__builtin_bit_cast(unsigned short, hq);
                    // partner h[p+1] lives at lane rt+2 -> xor-2 swizzle
                    const unsigned prt =
                        (unsigned)__builtin_amdgcn_ds_swizzle((int)hb, 0x081F) & 0xFFFFu;
                    if (!(p & 1))
                        __hip_atomic_store(ring + ((t >> 6) & 3) * CHUNK_DW
                                                + (t & 63) * 50 + (p >> 1),
                                           hb | (prt << 16), __ATOMIC_RELAXED,
                                           __HIP_MEMORY_SCOPE_AGENT);
                }
                if (((t & 63) == 63) || (t == TP - 1))
                    asm volatile("s_waitcnt vmcnt(0)" ::: "memory");
            } else if (t + 1 < TP) {                   // conv lanes: x(t+1)
                _Float16* nx1 = X1 + ((t & 1) ^ 1) * X1R;
                nx1[f1] = (_Float16)fmaxf(
                    fmaf(s_buf[t + 1], cv0, fmaf(s_buf[t + 2], cv1, cb0)), 0.f);
                if (f1 < 8)
                    nx1[56 + f1] = (_Float16)fmaxf(
                        fmaf(s_buf[t + 1], cv0b, fmaf(s_buf[t + 2], cv1b, cb0b)), 0.f);
            }
            step_barrier();                            // (C) 4-wave rendezvous
            if (tid == 0 && (((t & 63) == 63) || (t == TP - 1)))
                __hip_atomic_fetch_add(pflag, 1, __ATOMIC_RELEASE,
                                       __HIP_MEMORY_SCOPE_AGENT);
        }
    } else {
        // ====== CONSUMER block: LSTM2 + dense + softmax ======
        const int rt = tid;
        const int active = rt < 200;
        const int lrt = active ? rt : 0;
        const int p  = lrt >> 1;
        const int g2 = lrt & 1;
        const int cL = (2 * g2) * HH + p;

        h2 wa[100], wb[100];
        {
            const float4* w4 = (const float4*)(wpk + NPW + (size_t)lrt * 200);
#pragma unroll
            for (int j = 0; j < 50; ++j) {
                const float4 v = w4[j];
                wa[2*j]   = B2(v.x); wb[2*j]   = B2(v.y);
                wa[2*j+1] = B2(v.z); wb[2*j+1] = B2(v.w);
            }
        }
        const float bL = b2[cL], bH = b2[cL + HH];
        __syncthreads();                               // (B)

        float c = 0.0f;
        for (int k = 0; k < NCHUNK; ++k) {
            if (tid == 0) {                            // wait for producer chunk k
                int g = 0;
                while (__hip_atomic_load(pflag, __ATOMIC_ACQUIRE,
                                         __HIP_MEMORY_SCOPE_AGENT) < k + 1
                       && g < 50000000) { ++g; __builtin_amdgcn_s_sleep(8); }
            }
            __syncthreads();                           // chunk ready
            const int csz = (TP - (k << 6) < CHK) ? (TP - (k << 6)) : CHK;
            unsigned* gsrc = ring + (k & 3) * CHUNK_DW;
            for (int d = tid; d < csz * 50; d += 256)
                ((unsigned*)CB)[(d / 50) * 52 + (d % 50)] =
                    __hip_atomic_load(gsrc + d, __ATOMIC_RELAXED,
                                      __HIP_MEMORY_SCOPE_AGENT);
            __syncthreads();                           // staged
            if (tid == 0)
                __hip_atomic_fetch_add(aflag, 1, __ATOMIC_RELAXED,
                                       __HIP_MEMORY_SCOPE_AGENT);
            for (int lt = 0; lt < csz; ++lt) {
                const int t = (k << 6) + lt;
                if (active) {
                    float za0 = 0.f, za1 = 0.f, zb0 = 0.f, zb1 = 0.f;
                    CDOTH(CB + lt * CBQ, 0)            // h1 part (wa/wb[0..49])
                    CDOTH(HR + (t & 1) * CBQ, 50)      // h2 part (wa/wb[50..99])
                    const float zaS = za0 + za1 + bL;
                    const float zbS = zb0 + zb1 + bH;
                    float h;
                    GCELL1(zaS, zbS, c, h)
                    if (!g2)
                        HR[((t & 1) ^ 1) * CBQ + p] = (_Float16)h;
                }
                step_barrier();                        // (C) 4-wave rendezvous
            }
        }

        // final h2(t=2046) in slot ((2046&1)^1)=1
        if (rt == 0) {
            float l[3];
#pragma unroll
            for (int a = 0; a < 3; ++a) {
                float acc = db[a];
                for (int j = 0; j < HH; ++j)
                    acc = fmaf((float)HR[CBQ + j], dw[j * 3 + a], acc);
                l[a] = acc;
            }
            const float m = fmaxf(l[0], fmaxf(l[1], l[2]));
            const float e0 = __expf(l[0] - m), e1 = __expf(l[1] - m), e2 = __expf(l[2] - m);
            const float inv = 1.0f / (e0 + e1 + e2);
            out[b * 3 + 0] = e0 * inv;
            out[b * 3 + 1] = e1 * inv;
            out[b * 3 + 2] = e2 * inv;
        }
    }
}

// ---------------- launch ----------------------------------------------------
extern "C" void kernel_launch(void* const* d_in, const int* in_sizes, int n_in,
                              void* d_out, int out_size, void* d_ws, size_t ws_size,
                              hipStream_t stream) {
    const float* s      = (const float*)d_in[0];
    const float* conv_w = (const float*)d_in[1];
    const float* conv_b = (const float*)d_in[2];
    const float* w1     = (const float*)d_in[3];
    const float* u1     = (const float*)d_in[4];
    const float* b1     = (const float*)d_in[5];
    const float* w2     = (const float*)d_in[6];
    const float* u2     = (const float*)d_in[7];
    const float* b2     = (const float*)d_in[8];
    const float* dw     = (const float*)d_in[9];
    const float* db     = (const float*)d_in[10];

    h2* ws = (h2*)d_ws;
    hipMemsetAsync((void*)((int*)(ws + WS_FLAGS)), 0, 256 * sizeof(int), stream);
    const int nh2 = NPW + NCW;
    prep_weights<<<(nh2 + 255) / 256, 256, 0, stream>>>(w1, u1, w2, u2, ws);
    fused_lstm_kernel<<<256, 256, 0, stream>>>(
        s, conv_w, conv_b, b1, b2, dw, db, ws, (float*)d_out);
}

// Round 19
// 1856.459 us; speedup vs baseline: 1.7001x; 1.1613x over previous
//
#include <hip/hip_runtime.h>
#include <math.h>

// Conv1D(k=2,F=64,relu) -> LSTM1(H=100, relu cell, seq) -> LSTM2 (last) ->
// Dense(3) -> softmax.  B=128, T=2048, T'=2047.
//
// Round-24 = r20 (1844.6us best) + three local issue/chain micro-fixes.
//  Model (r19/r20/r22/r23): step = ~550cy sync/LDS-turnaround constant
//  (width- and drain-invariant) + ~400cy issue/chain (paid in full).
//  Attack the live term only:
//   1. __launch_bounds__(512,1): residency is 1 block/CU anyway; lift the
//      unforced 128-reg cap (r20 squeezed ~90 weight regs into 64V+64A).
//   2. 8 accumulator chains in PDOT/CDOT (was 4): chain depth 22-25 -> 11-13,
//      halving the ~90-100cy dependency tail per step.
//   3. Div-free consumer staging loop (was /50,%50 per iteration).
//  Everything else r20-byte-identical: layer-split pipeline, (p,g2,kh)
//  mapping, DPP psum2/xswap2, packed f16 weights, 4-slot ring, lgkmcnt-only
//  step_barrier, chunk-end vmcnt(0)+release.
//  Go/no-go: null (+-1%) -> 901ns step is the irreducible sync floor.

typedef _Float16 h2 __attribute__((ext_vector_type(2)));

#define TT 2048
#define TP 2047
#define HH 100
#define G4 400
#define FF 64
#define NB 128

#define X1R 176              // producer operand row halves (2x88)
#define CBQ 104              // consumer row halves (100 + pad4)
#define NPW (400 * 88)       // producer packed h2
#define NCW (400 * 100)      // consumer packed h2
#define CHK 64
#define NCHUNK 32
#define RINGC 4
#define CHUNK_DW (CHK * 50)  // 3200 dwords per ring slot

// ws layout in 4B units
#define WS_FLAGS (NPW + NCW)       // pflag[128], aflag[128]
#define WS_RING  (WS_FLAGS + 256)  // 128 * RINGC * CHUNK_DW dwords

#define FD2(w, xs, acc) acc = __builtin_amdgcn_fdot2(w, xs, acc, false)
#define B2(f) __builtin_bit_cast(h2, f)

// DPP quad_perm: 0xB1 = xor-1, 0x4E = xor-2 (proven r6-r23)
static __device__ __forceinline__ float psum2(float z) {
    int p = __builtin_amdgcn_update_dpp(0, __builtin_bit_cast(int, z),
                                        0xB1, 0xF, 0xF, true);
    return z + __builtin_bit_cast(float, p);
}
static __device__ __forceinline__ float xswap2(float z) {
    int p = __builtin_amdgcn_update_dpp(0, __builtin_bit_cast(int, z),
                                        0x4E, 0xF, 0xF, true);
    return __builtin_bit_cast(float, p);
}
static __device__ __forceinline__ float sig(float z) {
    return 1.0f / (1.0f + __expf(-z));
}
// per-step barrier: order LDS (lgkmcnt) but DO NOT drain vmcnt -- ring
// stores stay in flight across steps (drained once per chunk).
static __device__ __forceinline__ void step_barrier() {
    __builtin_amdgcn_sched_barrier(0);
    asm volatile("s_waitcnt lgkmcnt(0)" ::: "memory");
    __builtin_amdgcn_sched_barrier(0);
    __builtin_amdgcn_s_barrier();
    __builtin_amdgcn_sched_barrier(0);
}

// ---------------- prep kernel: pack weights f16 in per-thread order --------
// thread rt = (p<<2)|(g2<<1)|kh ; gates cL=(2*g2)*100+p, cH=cL+100.
// pack: float4 j = (a_{2j}, b_{2j}, a_{2j+1}, b_{2j+1})
__global__ void prep_weights(const float* __restrict__ w1, const float* __restrict__ u1,
                             const float* __restrict__ w2, const float* __restrict__ u2,
                             h2* __restrict__ ws)
{
    const int idx = blockIdx.x * 256 + threadIdx.x;
    if (idx >= NPW + NCW) return;
    float lo = 0.f, hi = 0.f;
    if (idx < NPW) {
        // producer: 88 h2/thread = 22 float4
        const int rt = idx / 88, r = idx % 88;
        const int qq = (r >> 2) * 2 + ((r & 3) >> 1);   // h2 pair index 0..43
        const int gs = r & 1;                           // 0 -> cL, 1 -> cH
        const int p = rt >> 2, g2 = (rt >> 1) & 1, kh = rt & 1;
        const int col = (2 * g2 + gs) * HH + p;
        const int E0 = 2 * qq;                          // in-half elem
#pragma unroll
        for (int e = 0; e < 2; ++e) {
            const int E = E0 + e;
            float v = 0.f;
            if (E < 82) {
                const int k = kh * 82 + E;              // orig combined-K index
                v = (k < FF) ? w1[k * G4 + col] : u1[(k - FF) * G4 + col];
            }
            if (e == 0) lo = v; else hi = v;
        }
    } else {
        // consumer: 100 h2/thread = 25 float4
        const int i2 = idx - NPW;
        const int rt = i2 / 100, r = i2 % 100;
        const int qq = (r >> 2) * 2 + ((r & 3) >> 1);   // 0..49
        const int gs = r & 1;
        const int p = rt >> 2, g2 = (rt >> 1) & 1, kh = rt & 1;
        const int col = (2 * g2 + gs) * HH + p;
        const int k0 = 2 * qq;
        const float* M = kh ? u2 : w2;
        lo = M[k0 * G4 + col];
        hi = M[(k0 + 1) * G4 + col];
    }
    ws[idx] = h2{(_Float16)lo, (_Float16)hi};
}

// ---------------- main kernel ----------------------------------------------
__global__ __launch_bounds__(512, 1)
void fused_lstm_kernel(const float* __restrict__ s,       // [B,T]
                       const float* __restrict__ conv_w,  // [2,1,F]
                       const float* __restrict__ conv_b,  // [F]
                       const float* __restrict__ b1,
                       const float* __restrict__ b2,
                       const float* __restrict__ dw, const float* __restrict__ db,
                       h2* __restrict__ wpk,              // weights + flags + ring
                       float* __restrict__ out)           // [B,3]
{
    const int tid  = threadIdx.x;
    const int bb   = blockIdx.x;
    const int b    = bb & (NB - 1);
    const bool prod = bb < NB;

    int* pflag = (int*)(wpk + WS_FLAGS) + b;
    int* aflag = (int*)(wpk + WS_FLAGS) + 128 + b;
    unsigned* ring = (unsigned*)(wpk + WS_RING) + (size_t)b * (RINGC * CHUNK_DW);

    __shared__ float s_buf[TT];                        // producer only
    __shared__ __align__(16) _Float16 X1[2 * X1R];     // producer operand ring
    __shared__ __align__(16) _Float16 CB[CHK * CBQ];   // consumer staged chunk
    __shared__ __align__(16) _Float16 HR[2 * CBQ];     // consumer h2 ring

    if (prod) {
        for (int i = tid; i < TT; i += 512) s_buf[i] = s[(size_t)b * TT + i];
        if (tid < X1R) ((unsigned*)X1)[tid] = 0u;      // both slots zero (pads stay 0)
    } else {
        if (tid < CBQ) ((unsigned*)HR)[tid] = 0u;      // 2*104 halves = 104 dwords
        if (tid < CHK * 2)                             // CB pad dwords [50,52)/row
            ((unsigned*)CB)[(tid >> 1) * 52 + 50 + (tid & 1)] = 0u;
    }
    __syncthreads();                                   // (A)

    if (prod) {
        // ================= PRODUCER block: conv + LSTM1 =================
        if (tid < 448) {
            const int rt = tid;
            const int active = rt < 400;
            const int lrt = active ? rt : 0;
            const int p  = lrt >> 2;
            const int g2 = (lrt >> 1) & 1;
            const int kh = lrt & 1;
            const int cL = (2 * g2) * HH + p;

            h2 wa[44], wb[44];
            {
                const float4* w4 = (const float4*)(wpk + (size_t)lrt * 88);
#pragma unroll
                for (int j = 0; j < 22; ++j) {
                    const float4 v = w4[j];
                    wa[2*j]   = B2(v.x); wb[2*j]   = B2(v.y);
                    wa[2*j+1] = B2(v.z); wb[2*j+1] = B2(v.w);
                }
            }
            const float bL = b1[cL], bH = b1[cL + HH];
            const int hoff = (p < 18) ? (64 + p) : (p + 70);  // h1[p] slot offset
            __syncthreads();                           // (B)

            float c = 0.0f;
            for (int t = 0; t < TP; ++t) {
                if ((t & 63) == 0) {                   // chunk start: ring credit
                    const int k = t >> 6;
                    if (tid == 0 && k >= RINGC) {
                        int g = 0;
                        while (__hip_atomic_load(aflag, __ATOMIC_ACQUIRE,
                                                 __HIP_MEMORY_SCOPE_AGENT) < k - (RINGC - 1)
                               && g < 50000000) { ++g; __builtin_amdgcn_s_sleep(8); }
                    }
                    __syncthreads();
                }
                if (active) {
                    _Float16* cur = X1 + (t & 1) * X1R;
                    _Float16* nx1 = X1 + ((t & 1) ^ 1) * X1R;
                    // 8 accumulator chains (depth 11 each)
                    float za0 = 0.f, za1 = 0.f, za2 = 0.f, za3 = 0.f;
                    float zb0 = 0.f, zb1 = 0.f, zb2 = 0.f, zb3 = 0.f;
                    const float4* vb = (const float4*)(cur + kh * 88);
#pragma unroll
                    for (int r2 = 0; r2 < 11; ++r2) {
                        const float4 v = vb[r2];
                        FD2(wa[4*r2+0], B2(v.x), za0); FD2(wb[4*r2+0], B2(v.x), zb0);
                        FD2(wa[4*r2+1], B2(v.y), za1); FD2(wb[4*r2+1], B2(v.y), zb1);
                        FD2(wa[4*r2+2], B2(v.z), za2); FD2(wb[4*r2+2], B2(v.z), zb2);
                        FD2(wa[4*r2+3], B2(v.w), za3); FD2(wb[4*r2+3], B2(v.w), zb3);
                    }
                    const float zaS = psum2((za0 + za1) + (za2 + za3)) + bL;
                    const float zbS = psum2((zb0 + zb1) + (zb2 + zb3)) + bH;
                    const float oa = xswap2(zaS), ob = xswap2(zbS);
                    const float zi = g2 ? oa  : zaS;
                    const float zf = g2 ? ob  : zbS;
                    const float zg = g2 ? zaS : oa;
                    const float zo = g2 ? zbS : ob;
                    c = fmaf(sig(zf), c, sig(zi) * fmaxf(zg, 0.f));
                    const float h = sig(zo) * fmaxf(c, 0.f);
                    if ((rt & 3) == 0) {
                        const _Float16 hq = (_Float16)h;
                        nx1[hoff] = hq;                // h1 for LSTM1(t+1)
                        const unsigned hb = (unsigned)__builtin_bit_cast(unsigned short, hq);
                        const unsigned prt =
                            (unsigned)__builtin_amdgcn_ds_swizzle((int)hb, 0x101F) & 0xFFFFu;
                        if (!(p & 1))
                            __hip_atomic_store(ring + ((t >> 6) & 3) * CHUNK_DW
                                                    + (t & 63) * 50 + (p >> 1),
                                               hb | (prt << 16), __ATOMIC_RELAXED,
                                               __HIP_MEMORY_SCOPE_AGENT);
                    }
                    if (((t & 63) == 63) || (t == TP - 1))
                        asm volatile("s_waitcnt vmcnt(0)" ::: "memory");
                }
                step_barrier();                        // (C) one per step (no vm drain)
                if (tid == 0 && (((t & 63) == 63) || (t == TP - 1)))
                    __hip_atomic_fetch_add(pflag, 1, __ATOMIC_RELEASE,
                                           __HIP_MEMORY_SCOPE_AGENT);
            }
        } else {
            // conv wave: threads 448-511, one filter each
            const int f = tid - 448;
            const float cv0 = conv_w[f], cv1 = conv_w[FF + f], cb0 = conv_b[f];
            X1[f] = (_Float16)fmaxf(fmaf(s_buf[0], cv0, fmaf(s_buf[1], cv1, cb0)), 0.f);
            __syncthreads();                           // (B)
            for (int t = 0; t < TP; ++t) {
                if ((t & 63) == 0) __syncthreads();    // chunk-start companion
                if (t + 1 < TP) {
                    _Float16* nx1 = X1 + ((t & 1) ^ 1) * X1R;
                    nx1[f] = (_Float16)fmaxf(
                        fmaf(s_buf[t + 1], cv0, fmaf(s_buf[t + 2], cv1, cb0)), 0.f);
                }
                step_barrier();                        // (C)
            }
        }
    } else {
        // ================= CONSUMER block: LSTM2 + dense + softmax ==========
        if (tid < 448) {
            const int rt = tid;
            const int active = rt < 400;
            const int lrt = active ? rt : 0;
            const int p  = lrt >> 2;
            const int g2 = (lrt >> 1) & 1;
            const int kh = lrt & 1;
            const int cL = (2 * g2) * HH + p;

            h2 wa[50], wb[50];
            {
                const float4* w4 = (const float4*)(wpk + NPW + (size_t)lrt * 100);
#pragma unroll
                for (int j = 0; j < 25; ++j) {
                    const float4 v = w4[j];
                    wa[2*j]   = B2(v.x); wb[2*j]   = B2(v.y);
                    wa[2*j+1] = B2(v.z); wb[2*j+1] = B2(v.w);
                }
            }
            const float bL = b2[cL], bH = b2[cL + HH];
            __syncthreads();                           // (B)

            float c = 0.0f;
            for (int k = 0; k < NCHUNK; ++k) {
                if (tid == 0) {                        // wait for producer chunk k
                    int g = 0;
                    while (__hip_atomic_load(pflag, __ATOMIC_ACQUIRE,
                                             __HIP_MEMORY_SCOPE_AGENT) < k + 1
                           && g < 50000000) { ++g; __builtin_amdgcn_s_sleep(8); }
                }
                __syncthreads();                       // chunk ready
                const int csz = (TP - (k << 6) < CHK) ? (TP - (k << 6)) : CHK;
                unsigned* gsrc = ring + (k & 3) * CHUNK_DW;
                {   // div-free staging: stride 448 = 8*50 + 48
                    int row = tid / 50, col = tid - row * 50;
                    for (int d = tid; d < csz * 50; d += 448) {
                        ((unsigned*)CB)[row * 52 + col] =
                            __hip_atomic_load(gsrc + d, __ATOMIC_RELAXED,
                                              __HIP_MEMORY_SCOPE_AGENT);
                        if (col < 2) { row += 8; col += 48; }
                        else         { row += 9; col -= 2;  }
                    }
                }
                __syncthreads();                       // staged
                if (tid == 0)
                    __hip_atomic_fetch_add(aflag, 1, __ATOMIC_RELAXED,
                                           __HIP_MEMORY_SCOPE_AGENT);
                for (int lt = 0; lt < csz; ++lt) {
                    const int t = (k << 6) + lt;
                    if (active) {
                        const _Float16* base = kh ? (HR + (t & 1) * CBQ)
                                                  : (CB + lt * CBQ);
                        // 8 accumulator chains (depth 12-13 each)
                        float za0 = 0.f, za1 = 0.f, za2 = 0.f, za3 = 0.f;
                        float zb0 = 0.f, zb1 = 0.f, zb2 = 0.f, zb3 = 0.f;
                        const float4* vb = (const float4*)base;
#pragma unroll
                        for (int r2 = 0; r2 < 12; ++r2) {
                            const float4 v = vb[r2];
                            FD2(wa[4*r2+0], B2(v.x), za0); FD2(wb[4*r2+0], B2(v.x), zb0);
                            FD2(wa[4*r2+1], B2(v.y), za1); FD2(wb[4*r2+1], B2(v.y), zb1);
                            FD2(wa[4*r2+2], B2(v.z), za2); FD2(wb[4*r2+2], B2(v.z), zb2);
                            FD2(wa[4*r2+3], B2(v.w), za3); FD2(wb[4*r2+3], B2(v.w), zb3);
                        }
                        {                              // tail halves 96..99
                            const float2 tv = *(const float2*)(base + 96);
                            FD2(wa[48], B2(tv.x), za0); FD2(wb[48], B2(tv.x), zb0);
                            FD2(wa[49], B2(tv.y), za1); FD2(wb[49], B2(tv.y), zb1);
                        }
                        const float zaS = psum2((za0 + za1) + (za2 + za3)) + bL;
                        const float zbS = psum2((zb0 + zb1) + (zb2 + zb3)) + bH;
                        const float oa = xswap2(zaS), ob = xswap2(zbS);
                        const float zi = g2 ? oa  : zaS;
                        const float zf = g2 ? ob  : zbS;
                        const float zg = g2 ? zaS : oa;
                        const float zo = g2 ? zbS : ob;
                        c = fmaf(sig(zf), c, sig(zi) * fmaxf(zg, 0.f));
                        const float h = sig(zo) * fmaxf(c, 0.f);
                        if ((rt & 3) == 0)
                            HR[((t & 1) ^ 1) * CBQ + p] = (_Float16)h;
                    }
                    step_barrier();                    // (C)
                }
            }

            // final h2(t=2046) was written into slot ((2046&1)^1)=1
            if (rt == 0) {
                float l[3];
#pragma unroll
                for (int a = 0; a < 3; ++a) {
                    float acc = db[a];
                    for (int j = 0; j < HH; ++j)
                        acc = fmaf((float)HR[CBQ + j], dw[j * 3 + a], acc);
                    l[a] = acc;
                }
                const float m = fmaxf(l[0], fmaxf(l[1], l[2]));
                const float e0 = __expf(l[0] - m), e1 = __expf(l[1] - m), e2 = __expf(l[2] - m);
                const float inv = 1.0f / (e0 + e1 + e2);
                out[b * 3 + 0] = e0 * inv;
                out[b * 3 + 1] = e1 * inv;
                out[b * 3 + 2] = e2 * inv;
            }
        } else {
            // threads 448-511: barrier companions
            __syncthreads();                           // (B)
            for (int k = 0; k < NCHUNK; ++k) {
                __syncthreads();                       // chunk ready
                const int csz = (TP - (k << 6) < CHK) ? (TP - (k << 6)) : CHK;
                __syncthreads();                       // staged
                for (int lt = 0; lt < csz; ++lt)
                    step_barrier();                    // (C)
            }
        }
    }
}

// ---------------- launch ----------------------------------------------------
extern "C" void kernel_launch(void* const* d_in, const int* in_sizes, int n_in,
                              void* d_out, int out_size, void* d_ws, size_t ws_size,
                              hipStream_t stream) {
    const float* s      = (const float*)d_in[0];
    const float* conv_w = (const float*)d_in[1];
    const float* conv_b = (const float*)d_in[2];
    const float* w1     = (const float*)d_in[3];
    const float* u1     = (const float*)d_in[4];
    const float* b1     = (const float*)d_in[5];
    const float* w2     = (const float*)d_in[6];
    const float* u2     = (const float*)d_in[7];
    const float* b2     = (const float*)d_in[8];
    const float* dw     = (const float*)d_in[9];
    const float* db     = (const float*)d_in[10];

    h2* ws = (h2*)d_ws;
    hipMemsetAsync((void*)((int*)(ws + WS_FLAGS)), 0, 256 * sizeof(int), stream);
    const int nh2 = NPW + NCW;
    prep_weights<<<(nh2 + 255) / 256, 256, 0, stream>>>(w1, u1, w2, u2, ws);
    fused_lstm_kernel<<<256, 512, 0, stream>>>(
        s, conv_w, conv_b, b1, b2, dw, db, ws, (float*)d_out);
}